// Round 13
// baseline (178.663 us; speedup 1.0000x reference)
//
#include <hip/hip_runtime.h>
#include <hip/hip_bf16.h>

typedef unsigned int uint;
typedef unsigned short ushort;
typedef short bf16x8_t __attribute__((ext_vector_type(8)));
typedef float f32x4_t __attribute__((ext_vector_type(4)));
typedef float f32x2_t __attribute__((ext_vector_type(2)));

// -------- bf16 helpers (manual, RNE) --------
__device__ __forceinline__ ushort f2bf(float f) {
    uint u = __float_as_uint(f);
    uint r = 0x7FFFu + ((u >> 16) & 1u);
    return (ushort)((u + r) >> 16);
}
__device__ __forceinline__ f32x2_t bfpair(uint w) {
    f32x2_t p;
    p.x = __uint_as_float(w << 16);
    p.y = __uint_as_float(w & 0xFFFF0000u);
    return p;
}
__device__ __forceinline__ void bf8_to_f(uint4 v, float* f) {
    f[0] = __uint_as_float(v.x << 16);
    f[1] = __uint_as_float(v.x & 0xFFFF0000u);
    f[2] = __uint_as_float(v.y << 16);
    f[3] = __uint_as_float(v.y & 0xFFFF0000u);
    f[4] = __uint_as_float(v.z << 16);
    f[5] = __uint_as_float(v.z & 0xFFFF0000u);
    f[6] = __uint_as_float(v.w << 16);
    f[7] = __uint_as_float(v.w & 0xFFFF0000u);
}
// -------- fp8 e4m3 (OCP) HW converts --------
__device__ __forceinline__ char f2fp8(float f) {
    int enc = __builtin_amdgcn_cvt_pk_fp8_f32(f, 0.f, 0, false);
    return (char)(enc & 0xFF);
}

// ==================== binned CSR build (coarse fixed-capacity buckets) ====================
// Bucket = dst >> 9 (512 nodes/bucket), K = 98 for N=50000. ebuf record: (dst&511)<<16 | src.
#define BKT_BITS 9
#define BKT_W    512
#define KMAX     128
#define CAP      18432   // mean 16326 + 16 sigma ; = 9 * 2048 (chunk-aligned)
#define SCHUNK   8192    // edges per scatter block
#define STHREADS 512
#define EPT      16      // edges per thread
#define CCHUNK   2048    // edges per finalize chunk
#define CPB      (CAP / CCHUNK)   // 9 chunks per bucket

__launch_bounds__(STHREADS)
__global__ void bucket_scatter(const int* __restrict__ src, const int* __restrict__ dst,
                               int* __restrict__ bpos, int* __restrict__ ebuf,
                               int E, int K) {
    __shared__ int h[KMAX];
    __shared__ int start[KMAX];
    int t = threadIdx.x;
    if (t < K) h[t] = 0;
    __syncthreads();
    int base = blockIdx.x * SCHUNK;

    uint rec[EPT];
#pragma unroll
    for (int u = 0; u < EPT; ++u) {
        int i = base + t + u * STHREADS;
        uint v = 0xFFFFFFFFu;
        if (i < E) {
            int d = dst[i];
            int b = d >> BKT_BITS;
            int r = atomicAdd(&h[b], 1);
            v = ((uint)b << 22) | ((uint)(d & (BKT_W - 1)) << 13) | (uint)r;
        }
        rec[u] = v;
    }
    __syncthreads();
    if (t < K) {
        int c = h[t];
        start[t] = c ? (t * CAP + atomicAdd(&bpos[t], c)) : 0;
    }
    __syncthreads();

#pragma unroll
    for (int u = 0; u < EPT; ++u) {
        uint v = rec[u];
        if (v != 0xFFFFFFFFu) {
            int i = base + t + u * STHREADS;
            int b = (int)(v >> 22);
            int lo = (int)((v >> 13) & (BKT_W - 1));
            int r = (int)(v & 0x1FFF);
            int p = start[b] + r;
            if (p < (b + 1) * CAP)
                ebuf[p] = src[i] | (lo << 16);
        }
    }
}

// ---- CSR finalize, full-GPU: deg count -> per-bucket scan -> placement ----

__launch_bounds__(256)
__global__ void csr_deg(const int* __restrict__ ebuf, const int* __restrict__ bpos,
                        int* __restrict__ cnt) {
    __shared__ int hist[BKT_W];
    int b = blockIdx.x / CPB;
    int c = blockIdx.x % CPB;
    int t = threadIdx.x;
    for (int i = t; i < BKT_W; i += 256) hist[i] = 0;
    __syncthreads();
    int base = b * CAP;
    int bcnt = min(bpos[b], CAP);
    int lo = c * CCHUNK;
    int end = min(bcnt, lo + CCHUNK);
    for (int i = lo + t; i < end; i += 256)
        atomicAdd(&hist[ebuf[base + i] >> 16], 1);
    __syncthreads();
    int node0 = b << BKT_BITS;
    for (int i = t; i < BKT_W; i += 256)
        if (hist[i]) atomicAdd(&cnt[node0 + i], hist[i]);
}

__launch_bounds__(BKT_W)
__global__ void csr_scan(const int* __restrict__ cnt, int* __restrict__ rp,
                         int* __restrict__ pos, float* __restrict__ dinv, int N) {
    __shared__ int sm[BKT_W];
    int b = blockIdx.x;
    int t = threadIdx.x;
    int node = (b << BKT_BITS) + t;
    int v = (node < N) ? cnt[node] : 0;
    sm[t] = v;
    __syncthreads();
    for (int o = 1; o < BKT_W; o <<= 1) {
        int u = (t >= o) ? sm[t - o] : 0;
        __syncthreads();
        sm[t] += u;
        __syncthreads();
    }
    if (node < N) {
        int p = b * CAP + (sm[t] - v);
        rp[node] = p;
        pos[node] = p;
        dinv[node] = rsqrtf((float)v + 1.0f);
    }
}

__launch_bounds__(256)
__global__ void csr_place(const int* __restrict__ ebuf, const int* __restrict__ bpos,
                          int* __restrict__ pos, ushort* __restrict__ col) {
    int b = blockIdx.x / CPB;
    int c = blockIdx.x % CPB;
    int t = threadIdx.x;
    int base = b * CAP;
    int bcnt = min(bpos[b], CAP);
    int lo = c * CCHUNK;
    int end = min(bcnt, lo + CCHUNK);
    int node0 = b << BKT_BITS;
    for (int i = lo + t; i < end; i += 256) {
        int p = ebuf[base + i];
        int node = node0 + (p >> 16);
        int w = atomicAdd(&pos[node], 1);
        col[w] = (ushort)(p & 0xFFFF);
    }
}

// ==================== W^T bf16 prep (+ bpos & cnt zeroing) ====================
__launch_bounds__(256)
__global__ void prep_wt(const float* __restrict__ W1, const float* __restrict__ W2,
                        ushort* __restrict__ wt1, ushort* __restrict__ wt2,
                        int* __restrict__ bpos, int* __restrict__ cnt, int N) {
    int t = blockIdx.x * 256 + threadIdx.x;
    if (t < 512) bpos[t] = 0;
    for (int i = t; i < N; i += 64 * 256) cnt[i] = 0;
    if (t < 128 * 128) {
        int n = t >> 7, k = t & 127;
        wt1[n * 128 + k] = f2bf(W1[k * 128 + n]);
    }
    if (t < 64 * 128) {
        int n = t >> 7, k = t & 127;
        wt2[n * 128 + k] = f2bf(W2[k * 64 + n]);
    }
}

// ==================== MFMA GEMM: Y[N,NC] = dinv .* (X[N,128] @ W[128,NC]) ====================

template <int NC, bool XBF16, bool OFP8>
__launch_bounds__(256)
__global__ void gemm_mfma(const void* __restrict__ Xv, const ushort* __restrict__ Wt,
                          const float* __restrict__ dinv, void* __restrict__ Yv, int N) {
    __shared__ ushort As[64 * 128];
    __shared__ ushort Bs[NC * 128];

    int tid = threadIdx.x;
    int r0 = blockIdx.x * 64;

    if (XBF16) {
        const uint4* X4 = (const uint4*)Xv;
#pragma unroll
        for (int j = 0; j < 4; ++j) {
            int idx = tid + j * 256;
            int lr = idx >> 4;
            int lc = idx & 15;
            int gr = r0 + lr;
            uint4 v = (gr < N) ? X4[(size_t)gr * 16 + lc] : make_uint4(0, 0, 0, 0);
            int boff = (lr * 256 + lc * 16) ^ ((lr & 7) << 4);
            *(uint4*)((char*)As + boff) = v;
        }
    } else {
        const float4* X4 = (const float4*)Xv;
#pragma unroll
        for (int j = 0; j < 8; ++j) {
            int idx = tid + j * 256;
            int lr = idx >> 5;
            int lc = idx & 31;
            int gr = r0 + lr;
            float4 v = (gr < N) ? X4[(size_t)gr * 32 + lc] : make_float4(0.f, 0.f, 0.f, 0.f);
            ushort4 o;
            o.x = f2bf(v.x); o.y = f2bf(v.y); o.z = f2bf(v.z); o.w = f2bf(v.w);
            int boff = (lr * 256 + lc * 8) ^ ((lr & 7) << 4);
            *(ushort4*)((char*)As + boff) = o;
        }
    }

    {
        const uint4* Wt4 = (const uint4*)Wt;
        constexpr int BSLOTS = NC * 16;
#pragma unroll
        for (int j = 0; j < BSLOTS / 256; ++j) {
            int idx = tid + j * 256;
            int n = idx >> 4;
            int c = idx & 15;
            uint4 v = Wt4[idx];
            int boff = (n * 256 + c * 16) ^ ((n & 7) << 4);
            *(uint4*)((char*)Bs + boff) = v;
        }
    }
    __syncthreads();

    int wave = tid >> 6;
    int lane = tid & 63;
    int l15 = lane & 15;
    int kgrp = lane >> 4;
    int arow = wave * 16 + l15;

    f32x4_t acc[NC / 16];
#pragma unroll
    for (int n = 0; n < NC / 16; ++n) acc[n] = (f32x4_t){0.f, 0.f, 0.f, 0.f};

#pragma unroll
    for (int ks = 0; ks < 4; ++ks) {
        int aoff = (arow * 256 + ks * 64 + kgrp * 16) ^ ((arow & 7) << 4);
        bf16x8_t a = *(const bf16x8_t*)((const char*)As + aoff);
#pragma unroll
        for (int n = 0; n < NC / 16; ++n) {
            int bcol = n * 16 + l15;
            int boff = (bcol * 256 + ks * 64 + kgrp * 16) ^ ((bcol & 7) << 4);
            bf16x8_t b = *(const bf16x8_t*)((const char*)Bs + boff);
            acc[n] = __builtin_amdgcn_mfma_f32_16x16x32_bf16(a, b, acc[n], 0, 0, 0);
        }
    }

    __syncthreads();   // Bs reads done; reuse as repack buffer

    float dr[4];
#pragma unroll
    for (int r = 0; r < 4; ++r) {
        int gr = r0 + wave * 16 + kgrp * 4 + r;
        dr[r] = (gr < N) ? dinv[gr] : 0.f;
    }

    if (OFP8) {
        char* Rs = (char*)Bs;
        constexpr int RSTB = 144;
#pragma unroll
        for (int n = 0; n < NC / 16; ++n)
#pragma unroll
            for (int r = 0; r < 4; ++r) {
                int row = wave * 16 + kgrp * 4 + r;
                int colc = n * 16 + l15;
                Rs[row * RSTB + colc] = f2fp8(acc[n][r] * dr[r]);
            }
        __syncthreads();
        constexpr int CPR = NC / 16;
        constexpr int OS = 64 * CPR;
#pragma unroll
        for (int j = 0; j < OS / 256; ++j) {
            int idx = tid + j * 256;
            int row = idx / CPR;
            int c = idx % CPR;
            int gr = r0 + row;
            if (gr < N)
                ((uint4*)Yv)[(size_t)gr * CPR + c] = *(const uint4*)&Rs[row * RSTB + c * 16];
        }
    } else {
        ushort* Rs = (ushort*)Bs;
        constexpr int RST = NC + 8;
#pragma unroll
        for (int n = 0; n < NC / 16; ++n)
#pragma unroll
            for (int r = 0; r < 4; ++r) {
                int row = wave * 16 + kgrp * 4 + r;
                int colc = n * 16 + l15;
                Rs[row * RST + colc] = f2bf(acc[n][r] * dr[r]);
            }
        __syncthreads();
        constexpr int CPR = NC / 8;
        constexpr int OS = 64 * CPR;
#pragma unroll
        for (int j = 0; j < OS / 256; ++j) {
            int idx = tid + j * 256;
            int row = idx / CPR;
            int c = idx % CPR;
            int gr = r0 + row;
            if (gr < N)
                ((uint4*)Yv)[(size_t)gr * CPR + c] = *(const uint4*)&Rs[row * RST + c * 8];
        }
    }
}

// ==================== layer-1 aggregation: fp8 pre-scaled rows, one wave/node ====================
// 64 lanes = 8 feature-lanes (16 feats) x 8 neighbor-slots. Packed f32x2 accumulation.

__device__ __forceinline__ void fp8_acc16(uint4 v, f32x2_t* acc) {
    acc[0] += __builtin_amdgcn_cvt_pk_f32_fp8((int)v.x, false);
    acc[1] += __builtin_amdgcn_cvt_pk_f32_fp8((int)v.x, true);
    acc[2] += __builtin_amdgcn_cvt_pk_f32_fp8((int)v.y, false);
    acc[3] += __builtin_amdgcn_cvt_pk_f32_fp8((int)v.y, true);
    acc[4] += __builtin_amdgcn_cvt_pk_f32_fp8((int)v.z, false);
    acc[5] += __builtin_amdgcn_cvt_pk_f32_fp8((int)v.z, true);
    acc[6] += __builtin_amdgcn_cvt_pk_f32_fp8((int)v.w, false);
    acc[7] += __builtin_amdgcn_cvt_pk_f32_fp8((int)v.w, true);
}

__launch_bounds__(256)
__global__ void agg_fp8_f128(const uint4* __restrict__ T4, const float* __restrict__ dinv,
                             const int* __restrict__ rp, const int* __restrict__ cnt,
                             const ushort* __restrict__ col, const float* __restrict__ bias,
                             ushort* __restrict__ O, int N) {
    int tid = threadIdx.x;
    int node = blockIdx.x * 4 + (tid >> 6);
    int lane = tid & 63;
    int f = lane & 7;
    int slot = lane >> 3;
    if (node >= N) return;

    f32x2_t acc[8];
#pragma unroll
    for (int i = 0; i < 8; ++i) acc[i] = (f32x2_t){0.f, 0.f};

    if (slot == 0) fp8_acc16(T4[node * 8 + f], acc);

    int start = rp[node];
    int num = cnt[node];
    int bk = 0;
    for (; bk + 16 <= num; bk += 16) {
        int j0 = col[start + bk + slot];
        int j1 = col[start + bk + 8 + slot];
        uint4 v0 = T4[j0 * 8 + f];
        uint4 v1 = T4[j1 * 8 + f];
        fp8_acc16(v0, acc);
        fp8_acc16(v1, acc);
    }
    for (int k = bk + slot; k < num; k += 8)
        fp8_acc16(T4[col[start + k] * 8 + f], acc);

#pragma unroll
    for (int i = 0; i < 8; ++i) {
        acc[i].x += __shfl_xor(acc[i].x, 8);
        acc[i].y += __shfl_xor(acc[i].y, 8);
        acc[i].x += __shfl_xor(acc[i].x, 16);
        acc[i].y += __shfl_xor(acc[i].y, 16);
        acc[i].x += __shfl_xor(acc[i].x, 32);
        acc[i].y += __shfl_xor(acc[i].y, 32);
    }

    if (slot == 0) {
        float di = dinv[node];
        uint o[8];
#pragma unroll
        for (int i = 0; i < 8; ++i) {
            float lo = fmaxf(fmaf(acc[i].x, di, bias[f * 16 + 2 * i]), 0.f);
            float hi = fmaxf(fmaf(acc[i].y, di, bias[f * 16 + 2 * i + 1]), 0.f);
            o[i] = (uint)f2bf(lo) | ((uint)f2bf(hi) << 16);
        }
        uint4* dst = (uint4*)&O[node * 128 + f * 16];
        dst[0] = make_uint4(o[0], o[1], o[2], o[3]);
        dst[1] = make_uint4(o[4], o[5], o[6], o[7]);
    }
}

// ==================== layer-2 aggregation: bf16 pre-scaled rows, one wave/node ====================

__device__ __forceinline__ void bf_acc8(uint4 v, f32x2_t* acc) {
    acc[0] += bfpair(v.x);
    acc[1] += bfpair(v.y);
    acc[2] += bfpair(v.z);
    acc[3] += bfpair(v.w);
}

__launch_bounds__(256)
__global__ void agg_bf16_f64(const ushort* __restrict__ Tb, const float* __restrict__ dinv,
                             const int* __restrict__ rp, const int* __restrict__ cnt,
                             const ushort* __restrict__ col, const float* __restrict__ bias,
                             ushort* __restrict__ O, int N) {
    int tid = threadIdx.x;
    int node = blockIdx.x * 4 + (tid >> 6);
    int lane = tid & 63;
    int f4 = lane & 7;
    int slot = lane >> 3;
    if (node >= N) return;

    const uint4* T4 = (const uint4*)Tb;

    f32x2_t acc[4];
#pragma unroll
    for (int i = 0; i < 4; ++i) acc[i] = (f32x2_t){0.f, 0.f};

    if (slot == 0) bf_acc8(T4[node * 8 + f4], acc);

    int start = rp[node];
    int num = cnt[node];
    int bk = 0;
    for (; bk + 16 <= num; bk += 16) {
        int j0 = col[start + bk + slot];
        int j1 = col[start + bk + 8 + slot];
        uint4 v0 = T4[j0 * 8 + f4];
        uint4 v1 = T4[j1 * 8 + f4];
        bf_acc8(v0, acc);
        bf_acc8(v1, acc);
    }
    for (int k = bk + slot; k < num; k += 8)
        bf_acc8(T4[col[start + k] * 8 + f4], acc);

#pragma unroll
    for (int i = 0; i < 4; ++i) {
        acc[i].x += __shfl_xor(acc[i].x, 8);
        acc[i].y += __shfl_xor(acc[i].y, 8);
        acc[i].x += __shfl_xor(acc[i].x, 16);
        acc[i].y += __shfl_xor(acc[i].y, 16);
        acc[i].x += __shfl_xor(acc[i].x, 32);
        acc[i].y += __shfl_xor(acc[i].y, 32);
    }

    if (slot == 0) {
        float di = dinv[node];
        uint o[4];
#pragma unroll
        for (int i = 0; i < 4; ++i) {
            float lo = fmaf(acc[i].x, di, bias[f4 * 8 + 2 * i]);
            float hi = fmaf(acc[i].y, di, bias[f4 * 8 + 2 * i + 1]);
            o[i] = (uint)f2bf(lo) | ((uint)f2bf(hi) << 16);
        }
        *(uint4*)&O[node * 64 + f4 * 8] = make_uint4(o[0], o[1], o[2], o[3]);
    }
}

// ==================== decode ====================

__launch_bounds__(256)
__global__ void decode_kernel(const ushort* __restrict__ Zb, const int* __restrict__ eli,
                              float* __restrict__ out, int EL) {
    int tid = threadIdx.x;
    int e = blockIdx.x * 32 + (tid >> 3);
    int f = tid & 7;
    if (e >= EL) return;
    int u = eli[e];
    int v = eli[EL + e];
    const uint4* Z4 = (const uint4*)Zb;
    float a[8], b[8];
    bf8_to_f(Z4[u * 8 + f], a);
    bf8_to_f(Z4[v * 8 + f], b);
    float s = 0.f;
#pragma unroll
    for (int i = 0; i < 8; ++i) s = fmaf(a[i], b[i], s);
    s += __shfl_xor(s, 1, 8);
    s += __shfl_xor(s, 2, 8);
    s += __shfl_xor(s, 4, 8);
    if (f == 0) out[e] = s;
}

// ==================== launch ====================

extern "C" void kernel_launch(void* const* d_in, const int* in_sizes, int n_in,
                              void* d_out, int out_size, void* d_ws, size_t ws_size,
                              hipStream_t stream) {
    const float* x   = (const float*)d_in[0];
    const int*   ei  = (const int*)d_in[1];
    const int*   eli = (const int*)d_in[2];
    const float* W1  = (const float*)d_in[3];
    const float* b1  = (const float*)d_in[4];
    const float* W2  = (const float*)d_in[5];
    const float* b2  = (const float*)d_in[6];
    float* out = (float*)d_out;

    int HID = in_sizes[4];
    int IN  = in_sizes[3] / HID;
    int N   = in_sizes[0] / IN;
    int E   = in_sizes[1] / 2;
    int EL  = in_sizes[2] / 2;
    int K   = (N + BKT_W - 1) >> BKT_BITS;

    char* ws = (char*)d_ws;
    auto carve = [&](size_t bytes) -> void* {
        void* p = (void*)ws;
        ws += (bytes + 255) & ~(size_t)255;
        return p;
    };
    int*    cnt   = (int*)carve((size_t)N * 4);
    float*  dinv  = (float*)carve((size_t)N * 4);
    int*    rp    = (int*)carve((size_t)N * 4);
    int*    pos   = (int*)carve((size_t)N * 4);
    int*    bpos  = (int*)carve(512 * 4);
    ushort* col   = (ushort*)carve((size_t)K * CAP * 2);
    ushort* wt1   = (ushort*)carve(128 * 128 * 2);
    ushort* wt2   = (ushort*)carve(64 * 128 * 2);
    // tbuf: layer1 = N*128 fp8 bytes ; layer2 = N*64 bf16 (same size 6.4 MB)
    void*   tbuf  = carve((size_t)N * 128);
    ushort* hbuf  = (ushort*)carve((size_t)N * 128 * 2);  // bf16 h (12.8 MB)
    ushort* zbuf  = (ushort*)carve((size_t)N * 64 * 2);   // bf16 z (6.4 MB)
    int*    ebuf  = (int*)hbuf;  // alias: K*CAP*4 = 7.2 MB <= 12.8 MB; dead before agg1 writes hbuf

    const int* src = ei;
    const int* dst = ei + E;

    prep_wt<<<64, 256, 0, stream>>>(W1, W2, wt1, wt2, bpos, cnt, N);
    bucket_scatter<<<(E + SCHUNK - 1) / SCHUNK, STHREADS, 0, stream>>>(src, dst, bpos, ebuf, E, K);
    csr_deg<<<K * CPB, 256, 0, stream>>>(ebuf, bpos, cnt);
    csr_scan<<<K, BKT_W, 0, stream>>>(cnt, rp, pos, dinv, N);
    csr_place<<<K * CPB, 256, 0, stream>>>(ebuf, bpos, pos, col);

    // layer 1: t1 = fp8(dinv .* (x@W1)) ; h = bf16(relu(dinv .* agg(t1) + b1))
    gemm_mfma<128, false, true><<<(N + 63) / 64, 256, 0, stream>>>(x, wt1, dinv, tbuf, N);
    agg_fp8_f128<<<(N + 3) / 4, 256, 0, stream>>>((const uint4*)tbuf, dinv, rp, cnt, col, b1, hbuf, N);

    // layer 2: t2 = bf16(dinv .* (h@W2)) ; z = bf16(dinv .* agg(t2) + b2)
    gemm_mfma<64, true, false><<<(N + 63) / 64, 256, 0, stream>>>(hbuf, wt2, dinv, tbuf, N);
    agg_bf16_f64<<<(N + 3) / 4, 256, 0, stream>>>((const ushort*)tbuf, dinv, rp, cnt, col, b2, zbuf, N);

    // decode
    decode_kernel<<<(EL + 31) / 32, 256, 0, stream>>>(zbuf, eli, out, EL);
}

// Round 14
// 139.384 us; speedup vs baseline: 1.2818x; 1.2818x over previous
//
#include <hip/hip_runtime.h>
#include <hip/hip_bf16.h>

typedef unsigned int uint;
typedef unsigned short ushort;
typedef short bf16x8_t __attribute__((ext_vector_type(8)));
typedef float f32x4_t __attribute__((ext_vector_type(4)));
typedef float f32x2_t __attribute__((ext_vector_type(2)));

// -------- bf16 helpers (manual, RNE) --------
__device__ __forceinline__ ushort f2bf(float f) {
    uint u = __float_as_uint(f);
    uint r = 0x7FFFu + ((u >> 16) & 1u);
    return (ushort)((u + r) >> 16);
}
__device__ __forceinline__ f32x2_t bfpair(uint w) {
    f32x2_t p;
    p.x = __uint_as_float(w << 16);
    p.y = __uint_as_float(w & 0xFFFF0000u);
    return p;
}
__device__ __forceinline__ void bf8_to_f(uint4 v, float* f) {
    f[0] = __uint_as_float(v.x << 16);
    f[1] = __uint_as_float(v.x & 0xFFFF0000u);
    f[2] = __uint_as_float(v.y << 16);
    f[3] = __uint_as_float(v.y & 0xFFFF0000u);
    f[4] = __uint_as_float(v.z << 16);
    f[5] = __uint_as_float(v.z & 0xFFFF0000u);
    f[6] = __uint_as_float(v.w << 16);
    f[7] = __uint_as_float(v.w & 0xFFFF0000u);
}
// -------- fp8 e4m3 (OCP) HW converts --------
__device__ __forceinline__ char f2fp8(float f) {
    int enc = __builtin_amdgcn_cvt_pk_fp8_f32(f, 0.f, 0, false);
    return (char)(enc & 0xFF);
}

// ==================== binned CSR build (fixed-capacity buckets) ====================
// Bucket = dst >> 8 (256 nodes/bucket), K = 196 for N=50000. ebuf record: (dst&255)<<16 | src.
#define BKT_BITS 8
#define BKT_W    256
#define KMAX     256
#define CAP      10240   // mean 8163 + ~16 sigma
#define SCHUNK   8192    // edges per scatter block
#define STHREADS 512
#define EPT      16      // edges per thread

__launch_bounds__(STHREADS)
__global__ void bucket_scatter(const int* __restrict__ src, const int* __restrict__ dst,
                               int* __restrict__ bpos, int* __restrict__ ebuf,
                               int E, int K) {
    __shared__ int h[KMAX];
    __shared__ int start[KMAX];
    int t = threadIdx.x;
    if (t < K) h[t] = 0;
    __syncthreads();
    int base = blockIdx.x * SCHUNK;

    // pass 1: read dst once, bucket + intra-block rank; cache packed (b,lo,rank)
    uint rec[EPT];
#pragma unroll
    for (int u = 0; u < EPT; ++u) {
        int i = base + t + u * STHREADS;
        uint v = 0xFFFFFFFFu;
        if (i < E) {
            int d = dst[i];
            int b = d >> BKT_BITS;
            int r = atomicAdd(&h[b], 1);
            v = ((uint)b << 22) | ((uint)(d & (BKT_W - 1)) << 13) | (uint)r;
        }
        rec[u] = v;
    }
    __syncthreads();
    if (t < K) {
        int c = h[t];
        start[t] = c ? (t * CAP + atomicAdd(&bpos[t], c)) : 0;
    }
    __syncthreads();

    // pass 2: read src, write contiguous per-bucket runs (~42 edges = 168B each)
#pragma unroll
    for (int u = 0; u < EPT; ++u) {
        uint v = rec[u];
        if (v != 0xFFFFFFFFu) {
            int i = base + t + u * STHREADS;
            int b = (int)(v >> 22);
            int lo = (int)((v >> 13) & 0x1FF);
            int r = (int)(v & 0x1FFF);
            int p = start[b] + r;
            if (p < (b + 1) * CAP)   // overflow guard (practically never)
                ebuf[p] = src[i] | (lo << 16);
        }
    }
}

// Monolithic per-bucket CSR finalize: one block per bucket keeps col writes
// single-owner (full-line fills). 196 blocks x 512 threads.
__launch_bounds__(512)
__global__ void bucket_csr(const int* __restrict__ ebuf, const int* __restrict__ bpos,
                           int* __restrict__ rp, int* __restrict__ cnt,
                           float* __restrict__ dinv, ushort* __restrict__ col, int N) {
    __shared__ int deg[BKT_W];
    __shared__ int off[BKT_W];
    int b = blockIdx.x;
    int t = threadIdx.x;
    int base = b * CAP;
    int end = base + min(bpos[b], CAP);
    if (t < BKT_W) deg[t] = 0;
    __syncthreads();
    for (int i = base + t; i < end; i += 512)
        atomicAdd(&deg[ebuf[i] >> 16], 1);
    __syncthreads();
    if (t < BKT_W) off[t] = deg[t];
    __syncthreads();
    for (int o = 1; o < BKT_W; o <<= 1) {
        int u = (t >= o && t < BKT_W) ? off[t - o] : 0;
        __syncthreads();
        if (t < BKT_W) off[t] += u;
        __syncthreads();
    }
    int node0 = b << BKT_BITS;
    if (t < BKT_W && node0 + t < N) {
        int ex = off[t] - deg[t];
        rp[node0 + t] = base + ex;
        cnt[node0 + t] = deg[t];
        dinv[node0 + t] = rsqrtf((float)deg[t] + 1.0f);
        off[t] = ex;
    }
    __syncthreads();
    for (int i = base + t; i < end; i += 512) {
        int p = ebuf[i];
        int r = atomicAdd(&off[p >> 16], 1);
        col[base + r] = (ushort)(p & 0xFFFF);
    }
}

// ==================== W^T bf16 prep (+ bpos zeroing) ====================
__launch_bounds__(256)
__global__ void prep_wt(const float* __restrict__ W1, const float* __restrict__ W2,
                        ushort* __restrict__ wt1, ushort* __restrict__ wt2,
                        int* __restrict__ bpos) {
    int t = blockIdx.x * 256 + threadIdx.x;
    if (t < KMAX) bpos[t] = 0;
    if (t < 128 * 128) {
        int n = t >> 7, k = t & 127;
        wt1[n * 128 + k] = f2bf(W1[k * 128 + n]);
    }
    if (t < 64 * 128) {
        int n = t >> 7, k = t & 127;
        wt2[n * 128 + k] = f2bf(W2[k * 64 + n]);
    }
}

// ==================== MFMA GEMM: Y[N,NC] = dinv .* (X[N,128] @ W[128,NC]) ====================

template <int NC, bool XBF16, bool OFP8>
__launch_bounds__(256)
__global__ void gemm_mfma(const void* __restrict__ Xv, const ushort* __restrict__ Wt,
                          const float* __restrict__ dinv, void* __restrict__ Yv, int N) {
    __shared__ ushort As[64 * 128];
    __shared__ ushort Bs[NC * 128];

    int tid = threadIdx.x;
    int r0 = blockIdx.x * 64;

    if (XBF16) {
        const uint4* X4 = (const uint4*)Xv;
#pragma unroll
        for (int j = 0; j < 4; ++j) {
            int idx = tid + j * 256;
            int lr = idx >> 4;
            int lc = idx & 15;
            int gr = r0 + lr;
            uint4 v = (gr < N) ? X4[(size_t)gr * 16 + lc] : make_uint4(0, 0, 0, 0);
            int boff = (lr * 256 + lc * 16) ^ ((lr & 7) << 4);
            *(uint4*)((char*)As + boff) = v;
        }
    } else {
        const float4* X4 = (const float4*)Xv;
#pragma unroll
        for (int j = 0; j < 8; ++j) {
            int idx = tid + j * 256;
            int lr = idx >> 5;
            int lc = idx & 31;
            int gr = r0 + lr;
            float4 v = (gr < N) ? X4[(size_t)gr * 32 + lc] : make_float4(0.f, 0.f, 0.f, 0.f);
            ushort4 o;
            o.x = f2bf(v.x); o.y = f2bf(v.y); o.z = f2bf(v.z); o.w = f2bf(v.w);
            int boff = (lr * 256 + lc * 8) ^ ((lr & 7) << 4);
            *(ushort4*)((char*)As + boff) = o;
        }
    }

    {
        const uint4* Wt4 = (const uint4*)Wt;
        constexpr int BSLOTS = NC * 16;
#pragma unroll
        for (int j = 0; j < BSLOTS / 256; ++j) {
            int idx = tid + j * 256;
            int n = idx >> 4;
            int c = idx & 15;
            uint4 v = Wt4[idx];
            int boff = (n * 256 + c * 16) ^ ((n & 7) << 4);
            *(uint4*)((char*)Bs + boff) = v;
        }
    }
    __syncthreads();

    int wave = tid >> 6;
    int lane = tid & 63;
    int l15 = lane & 15;
    int kgrp = lane >> 4;
    int arow = wave * 16 + l15;

    f32x4_t acc[NC / 16];
#pragma unroll
    for (int n = 0; n < NC / 16; ++n) acc[n] = (f32x4_t){0.f, 0.f, 0.f, 0.f};

#pragma unroll
    for (int ks = 0; ks < 4; ++ks) {
        int aoff = (arow * 256 + ks * 64 + kgrp * 16) ^ ((arow & 7) << 4);
        bf16x8_t a = *(const bf16x8_t*)((const char*)As + aoff);
#pragma unroll
        for (int n = 0; n < NC / 16; ++n) {
            int bcol = n * 16 + l15;
            int boff = (bcol * 256 + ks * 64 + kgrp * 16) ^ ((bcol & 7) << 4);
            bf16x8_t b = *(const bf16x8_t*)((const char*)Bs + boff);
            acc[n] = __builtin_amdgcn_mfma_f32_16x16x32_bf16(a, b, acc[n], 0, 0, 0);
        }
    }

    __syncthreads();   // Bs reads done; reuse as repack buffer

    float dr[4];
#pragma unroll
    for (int r = 0; r < 4; ++r) {
        int gr = r0 + wave * 16 + kgrp * 4 + r;
        dr[r] = (gr < N) ? dinv[gr] : 0.f;
    }

    if (OFP8) {
        char* Rs = (char*)Bs;
        constexpr int RSTB = 144;
#pragma unroll
        for (int n = 0; n < NC / 16; ++n)
#pragma unroll
            for (int r = 0; r < 4; ++r) {
                int row = wave * 16 + kgrp * 4 + r;
                int colc = n * 16 + l15;
                Rs[row * RSTB + colc] = f2fp8(acc[n][r] * dr[r]);
            }
        __syncthreads();
        constexpr int CPR = NC / 16;
        constexpr int OS = 64 * CPR;
#pragma unroll
        for (int j = 0; j < OS / 256; ++j) {
            int idx = tid + j * 256;
            int row = idx / CPR;
            int c = idx % CPR;
            int gr = r0 + row;
            if (gr < N)
                ((uint4*)Yv)[(size_t)gr * CPR + c] = *(const uint4*)&Rs[row * RSTB + c * 16];
        }
    } else {
        ushort* Rs = (ushort*)Bs;
        constexpr int RST = NC + 8;
#pragma unroll
        for (int n = 0; n < NC / 16; ++n)
#pragma unroll
            for (int r = 0; r < 4; ++r) {
                int row = wave * 16 + kgrp * 4 + r;
                int colc = n * 16 + l15;
                Rs[row * RST + colc] = f2bf(acc[n][r] * dr[r]);
            }
        __syncthreads();
        constexpr int CPR = NC / 8;
        constexpr int OS = 64 * CPR;
#pragma unroll
        for (int j = 0; j < OS / 256; ++j) {
            int idx = tid + j * 256;
            int row = idx / CPR;
            int c = idx % CPR;
            int gr = r0 + row;
            if (gr < N)
                ((uint4*)Yv)[(size_t)gr * CPR + c] = *(const uint4*)&Rs[row * RST + c * 8];
        }
    }
}

// ==================== layer-1 aggregation: fp8 pre-scaled rows, one wave/node ====================
// 64 lanes = 8 feature-lanes (16 feats) x 8 neighbor-slots. Packed f32x2 accumulation.

__device__ __forceinline__ void fp8_acc16(uint4 v, f32x2_t* acc) {
    acc[0] += __builtin_amdgcn_cvt_pk_f32_fp8((int)v.x, false);
    acc[1] += __builtin_amdgcn_cvt_pk_f32_fp8((int)v.x, true);
    acc[2] += __builtin_amdgcn_cvt_pk_f32_fp8((int)v.y, false);
    acc[3] += __builtin_amdgcn_cvt_pk_f32_fp8((int)v.y, true);
    acc[4] += __builtin_amdgcn_cvt_pk_f32_fp8((int)v.z, false);
    acc[5] += __builtin_amdgcn_cvt_pk_f32_fp8((int)v.z, true);
    acc[6] += __builtin_amdgcn_cvt_pk_f32_fp8((int)v.w, false);
    acc[7] += __builtin_amdgcn_cvt_pk_f32_fp8((int)v.w, true);
}

__launch_bounds__(256)
__global__ void agg_fp8_f128(const uint4* __restrict__ T4, const float* __restrict__ dinv,
                             const int* __restrict__ rp, const int* __restrict__ cnt,
                             const ushort* __restrict__ col, const float* __restrict__ bias,
                             ushort* __restrict__ O, int N) {
    int tid = threadIdx.x;
    int node = blockIdx.x * 4 + (tid >> 6);
    int lane = tid & 63;
    int f = lane & 7;
    int slot = lane >> 3;
    if (node >= N) return;

    f32x2_t acc[8];
#pragma unroll
    for (int i = 0; i < 8; ++i) acc[i] = (f32x2_t){0.f, 0.f};

    if (slot == 0) fp8_acc16(T4[node * 8 + f], acc);

    int start = rp[node];
    int num = cnt[node];
    int bk = 0;
    for (; bk + 16 <= num; bk += 16) {
        int j0 = col[start + bk + slot];
        int j1 = col[start + bk + 8 + slot];
        uint4 v0 = T4[j0 * 8 + f];
        uint4 v1 = T4[j1 * 8 + f];
        fp8_acc16(v0, acc);
        fp8_acc16(v1, acc);
    }
    for (int k = bk + slot; k < num; k += 8)
        fp8_acc16(T4[col[start + k] * 8 + f], acc);

#pragma unroll
    for (int i = 0; i < 8; ++i) {
        acc[i].x += __shfl_xor(acc[i].x, 8);
        acc[i].y += __shfl_xor(acc[i].y, 8);
        acc[i].x += __shfl_xor(acc[i].x, 16);
        acc[i].y += __shfl_xor(acc[i].y, 16);
        acc[i].x += __shfl_xor(acc[i].x, 32);
        acc[i].y += __shfl_xor(acc[i].y, 32);
    }

    if (slot == 0) {
        float di = dinv[node];
        uint o[8];
#pragma unroll
        for (int i = 0; i < 8; ++i) {
            float lo = fmaxf(fmaf(acc[i].x, di, bias[f * 16 + 2 * i]), 0.f);
            float hi = fmaxf(fmaf(acc[i].y, di, bias[f * 16 + 2 * i + 1]), 0.f);
            o[i] = (uint)f2bf(lo) | ((uint)f2bf(hi) << 16);
        }
        uint4* dst = (uint4*)&O[node * 128 + f * 16];
        dst[0] = make_uint4(o[0], o[1], o[2], o[3]);
        dst[1] = make_uint4(o[4], o[5], o[6], o[7]);
    }
}

// ==================== layer-2 aggregation: bf16 pre-scaled rows, one wave/node ====================

__device__ __forceinline__ void bf_acc8(uint4 v, f32x2_t* acc) {
    acc[0] += bfpair(v.x);
    acc[1] += bfpair(v.y);
    acc[2] += bfpair(v.z);
    acc[3] += bfpair(v.w);
}

__launch_bounds__(256)
__global__ void agg_bf16_f64(const ushort* __restrict__ Tb, const float* __restrict__ dinv,
                             const int* __restrict__ rp, const int* __restrict__ cnt,
                             const ushort* __restrict__ col, const float* __restrict__ bias,
                             ushort* __restrict__ O, int N) {
    int tid = threadIdx.x;
    int node = blockIdx.x * 4 + (tid >> 6);
    int lane = tid & 63;
    int f4 = lane & 7;
    int slot = lane >> 3;
    if (node >= N) return;

    const uint4* T4 = (const uint4*)Tb;

    f32x2_t acc[4];
#pragma unroll
    for (int i = 0; i < 4; ++i) acc[i] = (f32x2_t){0.f, 0.f};

    if (slot == 0) bf_acc8(T4[node * 8 + f4], acc);

    int start = rp[node];
    int num = cnt[node];
    int bk = 0;
    for (; bk + 16 <= num; bk += 16) {
        int j0 = col[start + bk + slot];
        int j1 = col[start + bk + 8 + slot];
        uint4 v0 = T4[j0 * 8 + f4];
        uint4 v1 = T4[j1 * 8 + f4];
        bf_acc8(v0, acc);
        bf_acc8(v1, acc);
    }
    for (int k = bk + slot; k < num; k += 8)
        bf_acc8(T4[col[start + k] * 8 + f4], acc);

#pragma unroll
    for (int i = 0; i < 4; ++i) {
        acc[i].x += __shfl_xor(acc[i].x, 8);
        acc[i].y += __shfl_xor(acc[i].y, 8);
        acc[i].x += __shfl_xor(acc[i].x, 16);
        acc[i].y += __shfl_xor(acc[i].y, 16);
        acc[i].x += __shfl_xor(acc[i].x, 32);
        acc[i].y += __shfl_xor(acc[i].y, 32);
    }

    if (slot == 0) {
        float di = dinv[node];
        uint o[4];
#pragma unroll
        for (int i = 0; i < 4; ++i) {
            float lo = fmaf(acc[i].x, di, bias[f4 * 8 + 2 * i]);
            float hi = fmaf(acc[i].y, di, bias[f4 * 8 + 2 * i + 1]);
            o[i] = (uint)f2bf(lo) | ((uint)f2bf(hi) << 16);
        }
        *(uint4*)&O[node * 64 + f4 * 8] = make_uint4(o[0], o[1], o[2], o[3]);
    }
}

// ==================== decode ====================

__launch_bounds__(256)
__global__ void decode_kernel(const ushort* __restrict__ Zb, const int* __restrict__ eli,
                              float* __restrict__ out, int EL) {
    int tid = threadIdx.x;
    int e = blockIdx.x * 32 + (tid >> 3);
    int f = tid & 7;
    if (e >= EL) return;
    int u = eli[e];
    int v = eli[EL + e];
    const uint4* Z4 = (const uint4*)Zb;
    float a[8], b[8];
    bf8_to_f(Z4[u * 8 + f], a);
    bf8_to_f(Z4[v * 8 + f], b);
    float s = 0.f;
#pragma unroll
    for (int i = 0; i < 8; ++i) s = fmaf(a[i], b[i], s);
    s += __shfl_xor(s, 1, 8);
    s += __shfl_xor(s, 2, 8);
    s += __shfl_xor(s, 4, 8);
    if (f == 0) out[e] = s;
}

// ==================== launch ====================

extern "C" void kernel_launch(void* const* d_in, const int* in_sizes, int n_in,
                              void* d_out, int out_size, void* d_ws, size_t ws_size,
                              hipStream_t stream) {
    const float* x   = (const float*)d_in[0];
    const int*   ei  = (const int*)d_in[1];
    const int*   eli = (const int*)d_in[2];
    const float* W1  = (const float*)d_in[3];
    const float* b1  = (const float*)d_in[4];
    const float* W2  = (const float*)d_in[5];
    const float* b2  = (const float*)d_in[6];
    float* out = (float*)d_out;

    int HID = in_sizes[4];
    int IN  = in_sizes[3] / HID;
    int N   = in_sizes[0] / IN;
    int E   = in_sizes[1] / 2;
    int EL  = in_sizes[2] / 2;
    int K   = (N + BKT_W - 1) >> BKT_BITS;

    char* ws = (char*)d_ws;
    auto carve = [&](size_t bytes) -> void* {
        void* p = (void*)ws;
        ws += (bytes + 255) & ~(size_t)255;
        return p;
    };
    int*    cnt   = (int*)carve((size_t)N * 4);
    float*  dinv  = (float*)carve((size_t)N * 4);
    int*    rp    = (int*)carve((size_t)N * 4);
    int*    bpos  = (int*)carve(KMAX * 4);
    ushort* col   = (ushort*)carve((size_t)K * CAP * 2);
    ushort* wt1   = (ushort*)carve(128 * 128 * 2);
    ushort* wt2   = (ushort*)carve(64 * 128 * 2);
    // tbuf: layer1 = N*128 fp8 bytes ; layer2 = N*64 bf16 (same size 6.4 MB)
    void*   tbuf  = carve((size_t)N * 128);
    ushort* hbuf  = (ushort*)carve((size_t)N * 128 * 2);  // bf16 h (12.8 MB)
    ushort* zbuf  = (ushort*)carve((size_t)N * 64 * 2);   // bf16 z (6.4 MB)
    int*    ebuf  = (int*)hbuf;  // alias: K*CAP*4 = 8.0 MB <= 12.8 MB; dead before agg1 writes hbuf

    const int* src = ei;
    const int* dst = ei + E;

    prep_wt<<<64, 256, 0, stream>>>(W1, W2, wt1, wt2, bpos);
    bucket_scatter<<<(E + SCHUNK - 1) / SCHUNK, STHREADS, 0, stream>>>(src, dst, bpos, ebuf, E, K);
    bucket_csr<<<K, 512, 0, stream>>>(ebuf, bpos, rp, cnt, dinv, col, N);

    // layer 1: t1 = fp8(dinv .* (x@W1)) ; h = bf16(relu(dinv .* agg(t1) + b1))
    gemm_mfma<128, false, true><<<(N + 63) / 64, 256, 0, stream>>>(x, wt1, dinv, tbuf, N);
    agg_fp8_f128<<<(N + 3) / 4, 256, 0, stream>>>((const uint4*)tbuf, dinv, rp, cnt, col, b1, hbuf, N);

    // layer 2: t2 = bf16(dinv .* (h@W2)) ; z = bf16(dinv .* agg(t2) + b2)
    gemm_mfma<64, true, false><<<(N + 63) / 64, 256, 0, stream>>>(hbuf, wt2, dinv, tbuf, N);
    agg_bf16_f64<<<(N + 3) / 4, 256, 0, stream>>>((const ushort*)tbuf, dinv, rp, cnt, col, b2, zbuf, N);

    // decode
    decode_kernel<<<(EL + 31) / 32, 256, 0, stream>>>(zbuf, eli, out, EL);
}